// Round 4
// baseline (345.314 us; speedup 1.0000x reference)
//
#include <hip/hip_runtime.h>
#include <math.h>

#define WAVE 64
constexpr int   CC      = 100;    // classes (fixed by problem)
constexpr int   MAXM    = 160;    // max thresholds per class (~0.05*P+1 ~= 132)
constexpr int   BUCKET  = 4096;   // per-class positive-score bucket capacity (P ~ 2621 +- 51)
constexpr int   USTRIDE = 161;    // LDS stride for u table (161 mod 32 != 0 -> spread banks)
constexpr int   LCAP    = 4096;   // per-block LDS compaction buffer (expected ~1300)
constexpr float LSMOOTH = 0.1f;
constexpr int   TILE    = 64;     // k1 rows per block
constexpr int   K3AGRID = 1024;
constexpr int   K3BGRID = 512;

// ---- K1 (fused k1b): LDS-tiled softmax stats + CE + direct bucket scatter ----
__global__ __launch_bounds__(256) void k1_tile(
    const float* __restrict__ pred, const int* __restrict__ targets,
    const float* __restrict__ weight, float* __restrict__ L_out,
    float* __restrict__ ce_partial, int* __restrict__ cls_cnt,
    float* __restrict__ bucket, int N)
{
    __shared__ float tile[TILE * CC];      // 25.6 KB
    __shared__ int   ttgt[TILE];
    __shared__ float tL[TILE], tpos[TILE];
    __shared__ float cered[4];
    __shared__ int   hist[CC], loc[CC], basec[CC];
    const int tid = threadIdx.x;
    const int r0  = blockIdx.x * TILE;

    // stage: 64 rows x 25 float4, fully coalesced
    const float4* src = (const float4*)(pred + (size_t)r0 * CC);
    #pragma unroll
    for (int t = tid; t < TILE * (CC / 4); t += 256)
        *((float4*)&tile[t * 4]) = src[t];
    if (tid < TILE) ttgt[tid] = targets[r0 + tid];
    for (int c = tid; c < CC; c += 256) { hist[c] = 0; loc[c] = 0; }
    __syncthreads();

    const int x = tid & 15;                // lane within 16-wide row group
    const int G = tid >> 4;                // group 0..15
    float w[7];
    #pragma unroll
    for (int j = 0; j < 7; ++j) {
        int c = x + 16 * j;
        w[j] = (c < CC) ? weight[c] : 0.0f;
    }
    float Wl = 0.0f;
    #pragma unroll
    for (int j = 0; j < 7; ++j) Wl += w[j];
    #pragma unroll
    for (int off = 1; off < 16; off <<= 1) Wl += __shfl_xor(Wl, off, 16);

    float ce_acc = 0.0f;
    #pragma unroll
    for (int rr = 0; rr < 4; ++rr) {
        const int r = G * 4 + rr;
        const float* rp = tile + r * CC;
        float v[7];
        #pragma unroll
        for (int j = 0; j < 7; ++j) {
            int c = x + 16 * j;
            v[j] = (c < CC) ? rp[c] : -INFINITY;
        }
        float vmax = v[0];
        #pragma unroll
        for (int j = 1; j < 7; ++j) vmax = fmaxf(vmax, v[j]);
        #pragma unroll
        for (int off = 1; off < 16; off <<= 1) vmax = fmaxf(vmax, __shfl_xor(vmax, off, 16));
        float z = 0.0f, ws = 0.0f;
        #pragma unroll
        for (int j = 0; j < 7; ++j) {
            int c = x + 16 * j;
            if (c < CC) { z += __expf(v[j] - vmax); ws += w[j] * v[j]; }
        }
        #pragma unroll
        for (int off = 1; off < 16; off <<= 1) {
            z  += __shfl_xor(z,  off, 16);
            ws += __shfl_xor(ws, off, 16);
        }
        float L = vmax + __logf(z);
        if (x == 0) {
            int t = ttgt[r];
            float pt = rp[t];
            tL[r] = L; tpos[r] = pt - L;
            atomicAdd(&hist[t], 1);
            ce_acc += -((1.0f - LSMOOTH) * weight[t] * (pt - L)
                        + (LSMOOTH / CC) * (ws - Wl * L));
        }
    }
    #pragma unroll
    for (int off = 32; off; off >>= 1) ce_acc += __shfl_xor(ce_acc, off, WAVE);
    if ((tid & 63) == 0) cered[tid >> 6] = ce_acc;
    __syncthreads();                           // hist, tL, tpos, cered complete

    // per-class global base, L writeback
    for (int c = tid; c < CC; c += 256)
        basec[c] = hist[c] ? atomicAdd(&cls_cnt[c], hist[c]) : 0;
    if (tid < TILE) L_out[r0 + tid] = tL[tid];
    if (tid == 0)
        ce_partial[blockIdx.x] = cered[0] + cered[1] + cered[2] + cered[3];
    __syncthreads();                           // basec ready

    if (tid < TILE) {                          // scatter this block's positives
        int c = ttgt[tid];
        int idx = basec[c] + atomicAdd(&loc[c], 1);
        if (idx < BUCKET) bucket[(size_t)c * BUCKET + idx] = tpos[tid];
    }
}

// --------- K2: per class, radix-select the m smallest positive scores ---------
__global__ __launch_bounds__(256) void k2_select(
    const float* __restrict__ bucket, const int* __restrict__ cls_cnt,
    float* __restrict__ u, int* __restrict__ m_arr, int* __restrict__ P_arr,
    float* __restrict__ wm_arr)
{
    __shared__ unsigned int keys[BUCKET];     // 16 KB
    __shared__ unsigned int hist[256];
    __shared__ unsigned int scan[256];
    __shared__ unsigned int sel[256];
    __shared__ unsigned int s_prefix;
    __shared__ int s_rank;
    __shared__ int cnt_lt;
    const int c   = blockIdx.x;
    const int tid = threadIdx.x;
    const int P = min(cls_cnt[c], BUCKET);
    double Kd = 0.95 * (double)P;
    int kf = (int)floor(Kd);
    int m = P - kf;
    if (m > MAXM) m = MAXM;
    if (m < 0) m = 0;
    if (tid == 0) {
        m_arr[c] = m; P_arr[c] = P;
        wm_arr[c] = (float)((double)(kf + 1) - Kd);   // fractional last-step weight
        s_prefix = 0; s_rank = m - 1; cnt_lt = 0;
    }
    for (int i = tid; i < P; i += 256) {
        unsigned int b = __float_as_uint(bucket[(size_t)c * BUCKET + i]);
        keys[i] = (b & 0x80000000u) ? ~b : (b | 0x80000000u);
    }
    __syncthreads();
    if (m == 0) return;

    for (int shift = 24; shift >= 0; shift -= 8) {
        hist[tid] = 0;
        __syncthreads();
        unsigned int pref = s_prefix;
        for (int i = tid; i < P; i += 256) {
            unsigned int k = keys[i];
            bool match = (shift == 24) || ((k >> (shift + 8)) == pref);
            if (match) atomicAdd(&hist[(k >> shift) & 255u], 1u);
        }
        __syncthreads();
        if (tid < 64) {   // single-wave inclusive scan of 256 bins (verified r1)
            unsigned h0 = hist[tid*4], h1 = hist[tid*4+1],
                     h2 = hist[tid*4+2], h3 = hist[tid*4+3];
            unsigned s0 = h0, s1 = s0 + h1, s2 = s1 + h2, s3 = s2 + h3;
            unsigned sc = s3;
            #pragma unroll
            for (int off = 1; off < 64; off <<= 1) {
                unsigned t2 = __shfl_up(sc, (unsigned)off, 64);
                if (tid >= off) sc += t2;
            }
            unsigned excl = sc - s3;
            scan[tid*4]   = excl + s0;
            scan[tid*4+1] = excl + s1;
            scan[tid*4+2] = excl + s2;
            scan[tid*4+3] = excl + s3;
        }
        __syncthreads();
        int r = s_rank;
        unsigned int inc = scan[tid];
        unsigned int exc = inc - hist[tid];
        __syncthreads();
        if ((unsigned int)r >= exc && (unsigned int)r < inc) {   // unique thread
            s_rank   = r - (int)exc;
            s_prefix = (pref << 8) | (unsigned int)tid;
        }
        __syncthreads();
    }
    const unsigned int kth = s_prefix;

    for (int i = tid; i < P; i += 256) {
        unsigned int k = keys[i];
        if (k < kth) {
            int pslot = atomicAdd(&cnt_lt, 1);
            sel[pslot] = k;
        }
    }
    __syncthreads();
    const int nlt = cnt_lt;
    for (int j = nlt + tid; j < 256; j += 256) sel[j] = (j < m) ? kth : 0xFFFFFFFFu;
    __syncthreads();
    for (int kk = 2; kk <= 256; kk <<= 1) {            // bitonic 256 ascending
        for (int j = kk >> 1; j > 0; j >>= 1) {
            int i = tid, ixj = tid ^ j;
            if (ixj > i) {
                unsigned int a = sel[i], b = sel[ixj];
                bool up = ((i & kk) == 0);
                if ((a > b) == up) { sel[i] = b; sel[ixj] = a; }
            }
            __syncthreads();
        }
    }
    if (tid < m) {
        unsigned int k = sel[tid];
        unsigned int b = (k & 0x80000000u) ? (k & 0x7fffffffu) : ~k;
        u[c * MAXM + tid] = __uint_as_float(b);        // m smallest, ascending
    }
}

// branchless uniform upper_bound over sorted prefix u[0..m-1]
__device__ __forceinline__ int ubound(const float* uc, int m, float key, int maxidx) {
    int l = 0;
    #pragma unroll
    for (int s = 128; s; s >>= 1) {
        int p = l + s - 1;
        float val = uc[p < maxidx ? p : maxidx];
        l += ((p < m) && (val <= key)) ? s : 0;
    }
    return l;
}

// --------- K3a: stream scores, per-lane LDS-atomic compaction (round-0 proven;
//           ballot aggregation measured 18 us slower) ---------
__global__ __launch_bounds__(256) void k3a_stream(
    const float4* __restrict__ pred4, const float* __restrict__ L,
    const float* __restrict__ u, const int* __restrict__ m_arr,
    uint2* __restrict__ list, int* __restrict__ list_cnt, int list_cap,
    int* __restrict__ g_cnt, int* __restrict__ g_sum, int total4)
{
    __shared__ float umax_s[CC];
    __shared__ uint2 buf[LCAP];               // 32 KB
    __shared__ int lcnt;
    __shared__ int gbase;
    const int tid = threadIdx.x;
    if (tid < CC) {
        int m = m_arr[tid];
        umax_s[tid] = (m > 0) ? u[tid * MAXM + m - 1] : -INFINITY;
    }
    if (tid == 0) lcnt = 0;
    __syncthreads();

    auto proc = [&](float4 v, float Ln, int j) {
        float4 um = *((const float4*)&umax_s[j * 4]);
        float s0 = v.x - Ln, s1 = v.y - Ln, s2 = v.z - Ln, s3 = v.w - Ln;
        #pragma unroll
        for (int q = 0; q < 4; ++q) {
            float scv = (q == 0) ? s0 : (q == 1) ? s1 : (q == 2) ? s2 : s3;
            float mx  = (q == 0) ? um.x : (q == 1) ? um.y : (q == 2) ? um.z : um.w;
            if (scv < mx) {
                int c = j * 4 + q;
                int idx = atomicAdd(&lcnt, 1);
                if (idx < LCAP) {
                    buf[idx] = make_uint2((unsigned int)c, __float_as_uint(scv));
                } else {                       // LDS overflow: inline exact rank
                    int m = m_arr[c];
                    int l = ubound(u + c * MAXM, m, scv, MAXM - 1);
                    atomicAdd(&g_cnt[c], 1);
                    atomicAdd(&g_sum[c], m - 1 - l);
                }
            }
        }
    };

    const int stride = K3AGRID * 256;          // 262144
    int i = blockIdx.x * 256 + tid;
    while (i < total4) {                       // 2-deep load ILP (round-0 proven)
        int i2 = i + stride;
        bool has2 = (i2 < total4);
        float4 v0 = pred4[i];
        float4 v1 = has2 ? pred4[i2] : make_float4(0.f, 0.f, 0.f, 0.f);
        int n0 = i / 25, j0 = i - n0 * 25;
        float L0 = L[n0];
        proc(v0, L0, j0);
        if (has2) {
            int n1 = i2 / 25, j1 = i2 - n1 * 25;
            proc(v1, L[n1], j1);
        }
        i += 2 * stride;
    }
    __syncthreads();
    int cnt = min(lcnt, LCAP);
    if (tid == 0) gbase = atomicAdd(list_cnt, cnt);
    __syncthreads();
    const int base0 = gbase;
    for (int k = tid; k < cnt; k += 256) {
        int gi = base0 + k;
        if (gi < list_cap) {
            list[gi] = buf[k];
        } else {                               // global overflow: inline exact
            uint2 e = buf[k];
            int c = (int)e.x; float scv = __uint_as_float(e.y);
            int m = m_arr[c];
            int l = ubound(u + c * MAXM, m, scv, MAXM - 1);
            atomicAdd(&g_cnt[c], 1);
            atomicAdd(&g_sum[c], m - 1 - l);
        }
    }
}

// --------- K3b: dense rank vs LDS u-table (4-way interleaved) + finalize ---------
__global__ __launch_bounds__(256) void k3b_rank_final(
    const uint2* __restrict__ list, const int* __restrict__ list_cnt, int list_cap,
    const float* __restrict__ u, const int* __restrict__ m_arr,
    const int* __restrict__ P_arr, const float* __restrict__ wm_arr,
    const float* __restrict__ weight, const float* __restrict__ ce_partial,
    int nPartial, int* __restrict__ g_cnt, int* __restrict__ g_sum,
    int* __restrict__ done, float* __restrict__ out, int N)
{
    __shared__ float us[CC * USTRIDE];         // 64.4 KB
    __shared__ int sm[CC], lcnt[CC], lsum[CC];
    __shared__ int lastflag;
    __shared__ double r1[256], r2[256], r3[256];
    const int tid = threadIdx.x;
    for (int c = tid; c < CC; c += 256) { sm[c] = m_arr[c]; lcnt[c] = 0; lsum[c] = 0; }
    for (int t = tid; t < CC * MAXM; t += 256) {
        int c = t / MAXM, k = t - c * MAXM;
        us[c * USTRIDE + k] = u[t];
    }
    __syncthreads();
    const int n = min(*list_cnt, list_cap);
    const int stride = K3BGRID * 256;
    for (int base = blockIdx.x * 256 + tid; base < n; base += 4 * stride) {
        int  cc4[4]; int mm4[4]; float kk4[4]; bool hh4[4];
        #pragma unroll
        for (int t = 0; t < 4; ++t) {
            int idx = base + t * stride;
            bool h = idx < n;
            uint2 e = h ? list[idx] : make_uint2(0u, 0u);
            hh4[t] = h;
            cc4[t] = (int)e.x;
            mm4[t] = h ? sm[(int)e.x] : 0;
            kk4[t] = __uint_as_float(e.y);
        }
        int ll4[4] = {0, 0, 0, 0};
        #pragma unroll
        for (int s = 128; s; s >>= 1) {        // 4 independent chains stepped together
            #pragma unroll
            for (int t = 0; t < 4; ++t) {
                int p = ll4[t] + s - 1;
                float val = us[cc4[t] * USTRIDE + (p < USTRIDE - 1 ? p : USTRIDE - 1)];
                ll4[t] += ((p < mm4[t]) && (val <= kk4[t])) ? s : 0;
            }
        }
        #pragma unroll
        for (int t = 0; t < 4; ++t)
            if (hh4[t]) {
                atomicAdd(&lcnt[cc4[t]], 1);
                atomicAdd(&lsum[cc4[t]], mm4[t] - 1 - ll4[t]);
            }
    }
    __syncthreads();
    for (int c = tid; c < CC; c += 256)
        if (lcnt[c]) { atomicAdd(&g_cnt[c], lcnt[c]); atomicAdd(&g_sum[c], lsum[c]); }
    __threadfence();
    __syncthreads();
    if (tid == 0) {
        int r = atomicAdd(done, 1);
        lastflag = (r == (int)gridDim.x - 1) ? 1 : 0;
    }
    __syncthreads();
    if (!lastflag) return;

    // ---------------- finalize (identical math to round-0 k4) ----------------
    double ce = 0.0;
    for (int t = tid; t < nPartial; t += 256) ce += (double)ce_partial[t];
    double p = 0.0, wsum = 0.0;
    for (int c = tid; c < CC; c += 256) {
        int P = P_arr[c], m = m_arr[c];
        double wgt = (double)weight[c];
        long long Nn = (long long)N - P;
        if (P > 0 && Nn > 0 && m > 0) {
            int gc = __hip_atomic_load(&g_cnt[c], __ATOMIC_RELAXED, __HIP_MEMORY_SCOPE_AGENT);
            int gs = __hip_atomic_load(&g_sum[c], __ATOMIC_RELAXED, __HIP_MEMORY_SCOPE_AGENT);
            double wm = (double)wm_arr[c];
            double S   = (double)gs + wm * (double)gc;
            double sub = 0.5 * (double)(m - 1) * (double)(m - 2) + wm * (double)(m - 1);
            double pc  = (S - sub) / ((double)Nn * (double)P);
            if (pc < 0.0) pc = 0.0;
            p += pc * wgt;
        }
        wsum += wgt;
    }
    r1[tid] = ce; r2[tid] = p; r3[tid] = wsum;
    __syncthreads();
    for (int off = 128; off; off >>= 1) {
        if (tid < off) {
            r1[tid] += r1[tid + off];
            r2[tid] += r2[tid + off];
            r3[tid] += r3[tid + off];
        }
        __syncthreads();
    }
    if (tid == 0) {
        double ce_loss = r1[0] / (double)N;
        double avg = r2[0] / (r3[0] * 0.05);           // MAX_PAUC = R1-R0 = 0.05
        avg = fmin(fmax(avg, 0.0), 1.0);
        out[0] = (float)(0.5 * ce_loss + 0.5 * (1.0 - avg * avg));
    }
}

extern "C" void kernel_launch(void* const* d_in, const int* in_sizes, int n_in,
                              void* d_out, int out_size, void* d_ws, size_t ws_size,
                              hipStream_t stream) {
    (void)n_in; (void)out_size;
    const float* pred    = (const float*)d_in[0];
    const int*   targets = (const int*)d_in[1];
    const float* weight  = (const float*)d_in[2];
    float* out = (float*)d_out;
    const int N = in_sizes[1];

    const int K1_BLOCKS = N / TILE;                    // 4096
    char* base = (char*)d_ws;
    size_t off = 0;
    auto take = [&](size_t bytes) { char* q = base + off; off += (bytes + 15) & ~(size_t)15; return q; };
    float* L_ws       = (float*)take((size_t)N * 4);
    float* ce_partial = (float*)take((size_t)K1_BLOCKS * 4);
    float* u          = (float*)take((size_t)CC * MAXM * 4);
    int*   m_arr      = (int*)take(CC * 4);
    int*   P_arr      = (int*)take(CC * 4);
    float* wm_arr     = (float*)take(CC * 4);
    int*   zero_blk   = (int*)take(304 * 4);           // cls_cnt|g_cnt|g_sum|list_cnt|done
    int*   cls_cnt  = zero_blk;
    int*   g_cnt    = zero_blk + CC;
    int*   g_sum    = zero_blk + 2 * CC;
    int*   list_cnt = zero_blk + 3 * CC;
    int*   done     = zero_blk + 3 * CC + 1;
    float* bucket     = (float*)take((size_t)CC * BUCKET * 4);   // 1.6 MB
    uint2* list       = (uint2*)(base + off);
    long long rem     = (long long)ws_size - (long long)off;
    int list_cap      = (rem > 0) ? (int)(rem / 8) : 0;          // expected need ~1.3M entries

    hipMemsetAsync(zero_blk, 0, 304 * 4, stream);

    k1_tile<<<K1_BLOCKS, 256, 0, stream>>>(pred, targets, weight, L_ws,
                                           ce_partial, cls_cnt, bucket, N);
    k2_select<<<CC, 256, 0, stream>>>(bucket, cls_cnt, u, m_arr, P_arr, wm_arr);
    const int total4 = (int)((size_t)N * CC / 4);
    k3a_stream<<<K3AGRID, 256, 0, stream>>>((const float4*)pred, L_ws, u, m_arr,
                                            list, list_cnt, list_cap, g_cnt, g_sum, total4);
    k3b_rank_final<<<K3BGRID, 256, 0, stream>>>(list, list_cnt, list_cap, u, m_arr,
                                                P_arr, wm_arr, weight, ce_partial,
                                                K1_BLOCKS, g_cnt, g_sum, done, out, N);
}

// Round 5
// 271.050 us; speedup vs baseline: 1.2740x; 1.2740x over previous
//
#include <hip/hip_runtime.h>
#include <math.h>

#define WAVE 64
constexpr int   CC      = 100;    // classes (fixed by problem)
constexpr int   MAXM    = 160;    // max thresholds per class (~0.05*P+1 ~= 132)
constexpr int   BUCKET  = 4096;   // per-class positive-score bucket capacity (P ~ 2621 +- 51)
constexpr int   USTRIDE = 161;    // LDS stride for u table (161 mod 32 != 0 -> spread banks)
constexpr int   LCAP    = 2048;   // per-block LDS compaction buffer (expect ~1293 +- 35)
constexpr float LSMOOTH = 0.1f;
constexpr int   TILE    = 64;     // k1 rows per block
constexpr int   T4TILE  = TILE * CC / 4;   // 1600 float4 per tile
constexpr int   K3AGRID = 1024;
constexpr int   K3BGRID = 512;

__device__ __forceinline__ void gload_lds16(const void* g, void* lds) {
    __builtin_amdgcn_global_load_lds(
        (const __attribute__((address_space(1))) void*)g,
        (__attribute__((address_space(3))) void*)lds, 16, 0, 0);
}

// ---------------- K1: LDS-tiled softmax stats (async gload_lds staging) ----------------
__global__ __launch_bounds__(256) void k1_tile(
    const float* __restrict__ pred, const int* __restrict__ targets,
    const float* __restrict__ weight, float* __restrict__ L_out,
    float* __restrict__ pos_out, float* __restrict__ ce_partial, int N)
{
    __shared__ float tile[TILE * CC];      // 25.6 KB
    __shared__ int   ttgt[TILE];
    __shared__ float tL[TILE], tpos[TILE];
    __shared__ float cered[4];
    const int tid = threadIdx.x;
    const int r0  = blockIdx.x * TILE;

    // stage: 64 rows x 25 float4 via direct global->LDS DMA; all 7 rounds in
    // flight concurrently, one vmcnt(0) drain (proven correct in R1 mega).
    const float4* src = (const float4*)(pred + (size_t)r0 * CC);
    {
        int t = tid;
        #pragma unroll
        for (int k = 0; k < T4TILE / 256; ++k) {      // 6 full rounds
            gload_lds16((const void*)(src + t), (char*)tile + (size_t)t * 16);
            t += 256;
        }
        if (t < T4TILE)                               // tail: wave 0 only
            gload_lds16((const void*)(src + t), (char*)tile + (size_t)t * 16);
    }
    if (tid < TILE) ttgt[tid] = targets[r0 + tid];
    asm volatile("s_waitcnt vmcnt(0)" ::: "memory");
    __syncthreads();

    const int x = tid & 15;                // lane within 16-wide row group
    const int G = tid >> 4;                // group 0..15
    float w[7];
    #pragma unroll
    for (int j = 0; j < 7; ++j) {
        int c = x + 16 * j;
        w[j] = (c < CC) ? weight[c] : 0.0f;
    }
    float Wl = 0.0f;
    #pragma unroll
    for (int j = 0; j < 7; ++j) Wl += w[j];
    #pragma unroll
    for (int off = 1; off < 16; off <<= 1) Wl += __shfl_xor(Wl, off, 16);

    float ce_acc = 0.0f;
    #pragma unroll
    for (int rr = 0; rr < 4; ++rr) {
        const int r = G * 4 + rr;
        const float* rp = tile + r * CC;
        float v[7];
        #pragma unroll
        for (int j = 0; j < 7; ++j) {
            int c = x + 16 * j;
            v[j] = (c < CC) ? rp[c] : -INFINITY;
        }
        float vmax = v[0];
        #pragma unroll
        for (int j = 1; j < 7; ++j) vmax = fmaxf(vmax, v[j]);
        #pragma unroll
        for (int off = 1; off < 16; off <<= 1) vmax = fmaxf(vmax, __shfl_xor(vmax, off, 16));
        float z = 0.0f, ws = 0.0f;
        #pragma unroll
        for (int j = 0; j < 7; ++j) {
            int c = x + 16 * j;
            if (c < CC) { z += __expf(v[j] - vmax); ws += w[j] * v[j]; }
        }
        #pragma unroll
        for (int off = 1; off < 16; off <<= 1) {
            z  += __shfl_xor(z,  off, 16);
            ws += __shfl_xor(ws, off, 16);
        }
        float L = vmax + __logf(z);
        if (x == 0) {
            int t = ttgt[r];
            float pt = rp[t];
            tL[r] = L; tpos[r] = pt - L;
            ce_acc += -((1.0f - LSMOOTH) * weight[t] * (pt - L)
                        + (LSMOOTH / CC) * (ws - Wl * L));
        }
    }
    #pragma unroll
    for (int off = 32; off; off >>= 1) ce_acc += __shfl_xor(ce_acc, off, WAVE);
    if ((tid & 63) == 0) cered[tid >> 6] = ce_acc;
    __syncthreads();
    if (tid < TILE) {                          // coalesced output
        L_out[r0 + tid]   = tL[tid];
        pos_out[r0 + tid] = tpos[tid];
    }
    if (tid == 0)
        ce_partial[blockIdx.x] = cered[0] + cered[1] + cered[2] + cered[3];
}

// ------- K1b: counting scatter of positive scores into per-class buckets -------
// (256 blocks: only 25.6K contended global atomics; R4 proved 4096-block
//  variant costs +70 us in cls_cnt atomic serialization)
__global__ __launch_bounds__(256) void k1b_scatter(
    const int* __restrict__ targets, const float* __restrict__ pos,
    int* __restrict__ cls_cnt, float* __restrict__ bucket, int N)
{
    __shared__ int hist[CC];
    __shared__ int base[CC];
    __shared__ int loc[CC];
    const int tid = threadIdx.x;
    const int rowsPerBlock = N / gridDim.x;
    const int r0 = blockIdx.x * rowsPerBlock;
    const int r1 = r0 + rowsPerBlock;
    for (int c = tid; c < CC; c += blockDim.x) { hist[c] = 0; loc[c] = 0; }
    __syncthreads();
    for (int r = r0 + tid; r < r1; r += blockDim.x)
        atomicAdd(&hist[targets[r]], 1);
    __syncthreads();
    for (int c = tid; c < CC; c += blockDim.x)
        base[c] = (hist[c] > 0) ? atomicAdd(&cls_cnt[c], hist[c]) : 0;
    __syncthreads();
    for (int r = r0 + tid; r < r1; r += blockDim.x) {
        int c = targets[r];
        int idx = base[c] + atomicAdd(&loc[c], 1);
        if (idx < BUCKET) bucket[(size_t)c * BUCKET + idx] = pos[r];
    }
}

// --------- K2: per class, radix-select the m smallest positive scores ---------
__global__ __launch_bounds__(256) void k2_select(
    const float* __restrict__ bucket, const int* __restrict__ cls_cnt,
    float* __restrict__ u, int* __restrict__ m_arr, int* __restrict__ P_arr,
    float* __restrict__ wm_arr)
{
    __shared__ unsigned int keys[BUCKET];     // 16 KB
    __shared__ unsigned int hist[256];
    __shared__ unsigned int scan[256];
    __shared__ unsigned int sel[256];
    __shared__ unsigned int s_prefix;
    __shared__ int s_rank;
    __shared__ int cnt_lt;
    const int c   = blockIdx.x;
    const int tid = threadIdx.x;
    const int P = min(cls_cnt[c], BUCKET);
    double Kd = 0.95 * (double)P;
    int kf = (int)floor(Kd);
    int m = P - kf;
    if (m > MAXM) m = MAXM;
    if (m < 0) m = 0;
    if (tid == 0) {
        m_arr[c] = m; P_arr[c] = P;
        wm_arr[c] = (float)((double)(kf + 1) - Kd);   // fractional last-step weight
        s_prefix = 0; s_rank = m - 1; cnt_lt = 0;
    }
    for (int i = tid; i < P; i += 256) {
        unsigned int b = __float_as_uint(bucket[(size_t)c * BUCKET + i]);
        keys[i] = (b & 0x80000000u) ? ~b : (b | 0x80000000u);
    }
    __syncthreads();
    if (m == 0) return;

    for (int shift = 24; shift >= 0; shift -= 8) {
        hist[tid] = 0;
        __syncthreads();
        unsigned int pref = s_prefix;
        for (int i = tid; i < P; i += 256) {
            unsigned int k = keys[i];
            bool match = (shift == 24) || ((k >> (shift + 8)) == pref);
            if (match) atomicAdd(&hist[(k >> shift) & 255u], 1u);
        }
        __syncthreads();
        if (tid < 64) {   // single-wave inclusive scan of 256 bins (verified r1)
            unsigned h0 = hist[tid*4], h1 = hist[tid*4+1],
                     h2 = hist[tid*4+2], h3 = hist[tid*4+3];
            unsigned s0 = h0, s1 = s0 + h1, s2 = s1 + h2, s3 = s2 + h3;
            unsigned sc = s3;
            #pragma unroll
            for (int off = 1; off < 64; off <<= 1) {
                unsigned t2 = __shfl_up(sc, (unsigned)off, 64);
                if (tid >= off) sc += t2;
            }
            unsigned excl = sc - s3;
            scan[tid*4]   = excl + s0;
            scan[tid*4+1] = excl + s1;
            scan[tid*4+2] = excl + s2;
            scan[tid*4+3] = excl + s3;
        }
        __syncthreads();
        int r = s_rank;
        unsigned int inc = scan[tid];
        unsigned int exc = inc - hist[tid];
        __syncthreads();
        if ((unsigned int)r >= exc && (unsigned int)r < inc) {   // unique thread
            s_rank   = r - (int)exc;
            s_prefix = (pref << 8) | (unsigned int)tid;
        }
        __syncthreads();
    }
    const unsigned int kth = s_prefix;

    for (int i = tid; i < P; i += 256) {
        unsigned int k = keys[i];
        if (k < kth) {
            int pslot = atomicAdd(&cnt_lt, 1);
            sel[pslot] = k;
        }
    }
    __syncthreads();
    const int nlt = cnt_lt;
    for (int j = nlt + tid; j < 256; j += 256) sel[j] = (j < m) ? kth : 0xFFFFFFFFu;
    __syncthreads();
    for (int kk = 2; kk <= 256; kk <<= 1) {            // bitonic 256 ascending
        for (int j = kk >> 1; j > 0; j >>= 1) {
            int i = tid, ixj = tid ^ j;
            if (ixj > i) {
                unsigned int a = sel[i], b = sel[ixj];
                bool up = ((i & kk) == 0);
                if ((a > b) == up) { sel[i] = b; sel[ixj] = a; }
            }
            __syncthreads();
        }
    }
    if (tid < m) {
        unsigned int k = sel[tid];
        unsigned int b = (k & 0x80000000u) ? (k & 0x7fffffffu) : ~k;
        u[c * MAXM + tid] = __uint_as_float(b);        // m smallest, ascending
    }
}

// branchless uniform upper_bound over sorted prefix u[0..m-1]
__device__ __forceinline__ int ubound(const float* uc, int m, float key, int maxidx) {
    int l = 0;
    #pragma unroll
    for (int s = 128; s; s >>= 1) {
        int p = l + s - 1;
        float val = uc[p < maxidx ? p : maxidx];
        l += ((p < m) && (val <= key)) ? s : 0;
    }
    return l;
}

// --------- K3a: stream scores, per-lane LDS-atomic compaction.
//           LCAP=2048 -> 17KB LDS -> 8 blocks/CU (100% occupancy). ---------
__global__ __launch_bounds__(256) void k3a_stream(
    const float4* __restrict__ pred4, const float* __restrict__ L,
    const float* __restrict__ u, const int* __restrict__ m_arr,
    uint2* __restrict__ list, int* __restrict__ list_cnt, int list_cap,
    int* __restrict__ g_cnt, int* __restrict__ g_sum, int total4)
{
    __shared__ float umax_s[CC];
    __shared__ uint2 buf[LCAP];               // 16 KB
    __shared__ int lcnt;
    __shared__ int gbase;
    const int tid = threadIdx.x;
    if (tid < CC) {
        int m = m_arr[tid];
        umax_s[tid] = (m > 0) ? u[tid * MAXM + m - 1] : -INFINITY;
    }
    if (tid == 0) lcnt = 0;
    __syncthreads();

    auto proc = [&](float4 v, float Ln, int j) {
        float4 um = *((const float4*)&umax_s[j * 4]);
        float s0 = v.x - Ln, s1 = v.y - Ln, s2 = v.z - Ln, s3 = v.w - Ln;
        #pragma unroll
        for (int q = 0; q < 4; ++q) {
            float scv = (q == 0) ? s0 : (q == 1) ? s1 : (q == 2) ? s2 : s3;
            float mx  = (q == 0) ? um.x : (q == 1) ? um.y : (q == 2) ? um.z : um.w;
            if (scv < mx) {
                int c = j * 4 + q;
                int idx = atomicAdd(&lcnt, 1);
                if (idx < LCAP) {
                    buf[idx] = make_uint2((unsigned int)c, __float_as_uint(scv));
                } else {                       // LDS overflow: inline exact rank
                    int m = m_arr[c];
                    int l = ubound(u + c * MAXM, m, scv, MAXM - 1);
                    atomicAdd(&g_cnt[c], 1);
                    atomicAdd(&g_sum[c], m - 1 - l);
                }
            }
        }
    };

    const int stride = K3AGRID * 256;          // 262144
    int i = blockIdx.x * 256 + tid;
    while (i < total4) {                       // 2-deep load ILP (round-0 proven)
        int i2 = i + stride;
        bool has2 = (i2 < total4);
        float4 v0 = pred4[i];
        float4 v1 = has2 ? pred4[i2] : make_float4(0.f, 0.f, 0.f, 0.f);
        int n0 = i / 25, j0 = i - n0 * 25;
        float L0 = L[n0];
        proc(v0, L0, j0);
        if (has2) {
            int n1 = i2 / 25, j1 = i2 - n1 * 25;
            proc(v1, L[n1], j1);
        }
        i += 2 * stride;
    }
    __syncthreads();
    int cnt = min(lcnt, LCAP);
    if (tid == 0) gbase = atomicAdd(list_cnt, cnt);
    __syncthreads();
    const int base0 = gbase;
    for (int k = tid; k < cnt; k += 256) {
        int gi = base0 + k;
        if (gi < list_cap) {
            list[gi] = buf[k];
        } else {                               // global overflow: inline exact
            uint2 e = buf[k];
            int c = (int)e.x; float scv = __uint_as_float(e.y);
            int m = m_arr[c];
            int l = ubound(u + c * MAXM, m, scv, MAXM - 1);
            atomicAdd(&g_cnt[c], 1);
            atomicAdd(&g_sum[c], m - 1 - l);
        }
    }
}

// --------- K3b: dense rank vs LDS u-table (4-way interleaved) + finalize ---------
__global__ __launch_bounds__(256) void k3b_rank_final(
    const uint2* __restrict__ list, const int* __restrict__ list_cnt, int list_cap,
    const float* __restrict__ u, const int* __restrict__ m_arr,
    const int* __restrict__ P_arr, const float* __restrict__ wm_arr,
    const float* __restrict__ weight, const float* __restrict__ ce_partial,
    int nPartial, int* __restrict__ g_cnt, int* __restrict__ g_sum,
    int* __restrict__ done, float* __restrict__ out, int N)
{
    __shared__ float us[CC * USTRIDE];         // 64.4 KB
    __shared__ int sm[CC], lcnt[CC], lsum[CC];
    __shared__ int lastflag;
    __shared__ double r1[256], r2[256], r3[256];
    const int tid = threadIdx.x;
    for (int c = tid; c < CC; c += 256) { sm[c] = m_arr[c]; lcnt[c] = 0; lsum[c] = 0; }
    for (int t = tid; t < CC * MAXM; t += 256) {
        int c = t / MAXM, k = t - c * MAXM;
        us[c * USTRIDE + k] = u[t];
    }
    __syncthreads();
    const int n = min(*list_cnt, list_cap);
    const int stride = K3BGRID * 256;
    for (int base = blockIdx.x * 256 + tid; base < n; base += 4 * stride) {
        int  cc4[4]; int mm4[4]; float kk4[4]; bool hh4[4];
        #pragma unroll
        for (int t = 0; t < 4; ++t) {
            int idx = base + t * stride;
            bool h = idx < n;
            uint2 e = h ? list[idx] : make_uint2(0u, 0u);
            hh4[t] = h;
            cc4[t] = (int)e.x;
            mm4[t] = h ? sm[(int)e.x] : 0;
            kk4[t] = __uint_as_float(e.y);
        }
        int ll4[4] = {0, 0, 0, 0};
        #pragma unroll
        for (int s = 128; s; s >>= 1) {        // 4 independent chains stepped together
            #pragma unroll
            for (int t = 0; t < 4; ++t) {
                int p = ll4[t] + s - 1;
                float val = us[cc4[t] * USTRIDE + (p < USTRIDE - 1 ? p : USTRIDE - 1)];
                ll4[t] += ((p < mm4[t]) && (val <= kk4[t])) ? s : 0;
            }
        }
        #pragma unroll
        for (int t = 0; t < 4; ++t)
            if (hh4[t]) {
                atomicAdd(&lcnt[cc4[t]], 1);
                atomicAdd(&lsum[cc4[t]], mm4[t] - 1 - ll4[t]);
            }
    }
    __syncthreads();
    for (int c = tid; c < CC; c += 256)
        if (lcnt[c]) { atomicAdd(&g_cnt[c], lcnt[c]); atomicAdd(&g_sum[c], lsum[c]); }
    __threadfence();
    __syncthreads();
    if (tid == 0) {
        int r = atomicAdd(done, 1);
        lastflag = (r == (int)gridDim.x - 1) ? 1 : 0;
    }
    __syncthreads();
    if (!lastflag) return;

    // ---------------- finalize (identical math to round-0 k4) ----------------
    double ce = 0.0;
    for (int t = tid; t < nPartial; t += 256) ce += (double)ce_partial[t];
    double p = 0.0, wsum = 0.0;
    for (int c = tid; c < CC; c += 256) {
        int P = P_arr[c], m = m_arr[c];
        double wgt = (double)weight[c];
        long long Nn = (long long)N - P;
        if (P > 0 && Nn > 0 && m > 0) {
            int gc = __hip_atomic_load(&g_cnt[c], __ATOMIC_RELAXED, __HIP_MEMORY_SCOPE_AGENT);
            int gs = __hip_atomic_load(&g_sum[c], __ATOMIC_RELAXED, __HIP_MEMORY_SCOPE_AGENT);
            double wm = (double)wm_arr[c];
            double S   = (double)gs + wm * (double)gc;
            double sub = 0.5 * (double)(m - 1) * (double)(m - 2) + wm * (double)(m - 1);
            double pc  = (S - sub) / ((double)Nn * (double)P);
            if (pc < 0.0) pc = 0.0;
            p += pc * wgt;
        }
        wsum += wgt;
    }
    r1[tid] = ce; r2[tid] = p; r3[tid] = wsum;
    __syncthreads();
    for (int off = 128; off; off >>= 1) {
        if (tid < off) {
            r1[tid] += r1[tid + off];
            r2[tid] += r2[tid + off];
            r3[tid] += r3[tid + off];
        }
        __syncthreads();
    }
    if (tid == 0) {
        double ce_loss = r1[0] / (double)N;
        double avg = r2[0] / (r3[0] * 0.05);           // MAX_PAUC = R1-R0 = 0.05
        avg = fmin(fmax(avg, 0.0), 1.0);
        out[0] = (float)(0.5 * ce_loss + 0.5 * (1.0 - avg * avg));
    }
}

extern "C" void kernel_launch(void* const* d_in, const int* in_sizes, int n_in,
                              void* d_out, int out_size, void* d_ws, size_t ws_size,
                              hipStream_t stream) {
    (void)n_in; (void)out_size;
    const float* pred    = (const float*)d_in[0];
    const int*   targets = (const int*)d_in[1];
    const float* weight  = (const float*)d_in[2];
    float* out = (float*)d_out;
    const int N = in_sizes[1];

    const int K1_BLOCKS = N / TILE;                    // 4096
    char* base = (char*)d_ws;
    size_t off = 0;
    auto take = [&](size_t bytes) { char* q = base + off; off += (bytes + 15) & ~(size_t)15; return q; };
    float* L_ws       = (float*)take((size_t)N * 4);
    float* pos_ws     = (float*)take((size_t)N * 4);
    float* ce_partial = (float*)take((size_t)K1_BLOCKS * 4);
    float* u          = (float*)take((size_t)CC * MAXM * 4);
    int*   m_arr      = (int*)take(CC * 4);
    int*   P_arr      = (int*)take(CC * 4);
    float* wm_arr     = (float*)take(CC * 4);
    int*   zero_blk   = (int*)take(304 * 4);           // cls_cnt|g_cnt|g_sum|list_cnt|done
    int*   cls_cnt  = zero_blk;
    int*   g_cnt    = zero_blk + CC;
    int*   g_sum    = zero_blk + 2 * CC;
    int*   list_cnt = zero_blk + 3 * CC;
    int*   done     = zero_blk + 3 * CC + 1;
    float* bucket     = (float*)take((size_t)CC * BUCKET * 4);   // 1.6 MB
    uint2* list       = (uint2*)(base + off);
    long long rem     = (long long)ws_size - (long long)off;
    int list_cap      = (rem > 0) ? (int)(rem / 8) : 0;          // expected need ~1.3M entries

    hipMemsetAsync(zero_blk, 0, 304 * 4, stream);

    k1_tile<<<K1_BLOCKS, 256, 0, stream>>>(pred, targets, weight, L_ws, pos_ws,
                                           ce_partial, N);
    k1b_scatter<<<256, 256, 0, stream>>>(targets, pos_ws, cls_cnt, bucket, N);
    k2_select<<<CC, 256, 0, stream>>>(bucket, cls_cnt, u, m_arr, P_arr, wm_arr);
    const int total4 = (int)((size_t)N * CC / 4);
    k3a_stream<<<K3AGRID, 256, 0, stream>>>((const float4*)pred, L_ws, u, m_arr,
                                            list, list_cnt, list_cap, g_cnt, g_sum, total4);
    k3b_rank_final<<<K3BGRID, 256, 0, stream>>>(list, list_cnt, list_cap, u, m_arr,
                                                P_arr, wm_arr, weight, ce_partial,
                                                K1_BLOCKS, g_cnt, g_sum, done, out, N);
}

// Round 7
// 254.438 us; speedup vs baseline: 1.3572x; 1.0653x over previous
//
#include <hip/hip_runtime.h>
#include <math.h>

#define WAVE 64
constexpr int   CC      = 100;    // classes (fixed by problem)
constexpr int   MAXM    = 160;    // max thresholds per class (~0.05*P+1 ~= 132)
constexpr int   BUCKET  = 4096;   // per-class positive-score bucket capacity (P ~ 2621 +- 51)
constexpr int   USTRIDE = 161;    // LDS stride for u table (161 mod 32 != 0 -> spread banks)
constexpr int   LCAP    = 2048;   // per-block LDS compaction buffer (expect ~1293 +- 35)
constexpr float LSMOOTH = 0.1f;
constexpr int   TILE    = 64;     // k1 rows per block
constexpr int   T4TILE  = TILE * CC / 4;   // 1600 float4 per tile
constexpr int   K3AGRID = 1024;
constexpr int   K3BGRID = 512;

__device__ __forceinline__ void gload_lds16(const void* g, void* lds) {
    __builtin_amdgcn_global_load_lds(
        (const __attribute__((address_space(1))) void*)g,
        (__attribute__((address_space(3))) void*)lds, 16, 0, 0);
}

// ---------------- K1: LDS-tiled softmax stats (async gload_lds staging) ----------------
__global__ __launch_bounds__(256) void k1_tile(
    const float* __restrict__ pred, const int* __restrict__ targets,
    const float* __restrict__ weight, float* __restrict__ L_out,
    float* __restrict__ pos_out, float* __restrict__ ce_partial, int N)
{
    __shared__ float tile[TILE * CC];      // 25.6 KB
    __shared__ int   ttgt[TILE];
    __shared__ float tL[TILE], tpos[TILE];
    __shared__ float cered[4];
    const int tid = threadIdx.x;
    const int r0  = blockIdx.x * TILE;

    // stage: 64 rows x 25 float4 via direct global->LDS DMA; all 7 rounds in
    // flight concurrently, one vmcnt(0) drain (proven R5: k1 131 -> <60 us).
    const float4* src = (const float4*)(pred + (size_t)r0 * CC);
    {
        int t = tid;
        #pragma unroll
        for (int k = 0; k < T4TILE / 256; ++k) {      // 6 full rounds
            gload_lds16((const void*)(src + t), (char*)tile + (size_t)t * 16);
            t += 256;
        }
        if (t < T4TILE)                               // tail: wave 0 only
            gload_lds16((const void*)(src + t), (char*)tile + (size_t)t * 16);
    }
    if (tid < TILE) ttgt[tid] = targets[r0 + tid];
    asm volatile("s_waitcnt vmcnt(0)" ::: "memory");
    __syncthreads();

    const int x = tid & 15;                // lane within 16-wide row group
    const int G = tid >> 4;                // group 0..15
    float w[7];
    #pragma unroll
    for (int j = 0; j < 7; ++j) {
        int c = x + 16 * j;
        w[j] = (c < CC) ? weight[c] : 0.0f;
    }
    float Wl = 0.0f;
    #pragma unroll
    for (int j = 0; j < 7; ++j) Wl += w[j];
    #pragma unroll
    for (int off = 1; off < 16; off <<= 1) Wl += __shfl_xor(Wl, off, 16);

    float ce_acc = 0.0f;
    #pragma unroll
    for (int rr = 0; rr < 4; ++rr) {
        const int r = G * 4 + rr;
        const float* rp = tile + r * CC;
        float v[7];
        #pragma unroll
        for (int j = 0; j < 7; ++j) {
            int c = x + 16 * j;
            v[j] = (c < CC) ? rp[c] : -INFINITY;
        }
        float vmax = v[0];
        #pragma unroll
        for (int j = 1; j < 7; ++j) vmax = fmaxf(vmax, v[j]);
        #pragma unroll
        for (int off = 1; off < 16; off <<= 1) vmax = fmaxf(vmax, __shfl_xor(vmax, off, 16));
        float z = 0.0f, ws = 0.0f;
        #pragma unroll
        for (int j = 0; j < 7; ++j) {
            int c = x + 16 * j;
            if (c < CC) { z += __expf(v[j] - vmax); ws += w[j] * v[j]; }
        }
        #pragma unroll
        for (int off = 1; off < 16; off <<= 1) {
            z  += __shfl_xor(z,  off, 16);
            ws += __shfl_xor(ws, off, 16);
        }
        float L = vmax + __logf(z);
        if (x == 0) {
            int t = ttgt[r];
            float pt = rp[t];
            tL[r] = L; tpos[r] = pt - L;
            ce_acc += -((1.0f - LSMOOTH) * weight[t] * (pt - L)
                        + (LSMOOTH / CC) * (ws - Wl * L));
        }
    }
    #pragma unroll
    for (int off = 32; off; off >>= 1) ce_acc += __shfl_xor(ce_acc, off, WAVE);
    if ((tid & 63) == 0) cered[tid >> 6] = ce_acc;
    __syncthreads();
    if (tid < TILE) {                          // coalesced output
        L_out[r0 + tid]   = tL[tid];
        pos_out[r0 + tid] = tpos[tid];
    }
    if (tid == 0)
        ce_partial[blockIdx.x] = cered[0] + cered[1] + cered[2] + cered[3];
}

// ------- K1b: counting scatter of positive scores into per-class buckets -------
// (256 blocks: only 25.6K contended global atomics; R4 proved 4096-block
//  variant costs +70 us in cls_cnt atomic serialization)
__global__ __launch_bounds__(256) void k1b_scatter(
    const int* __restrict__ targets, const float* __restrict__ pos,
    int* __restrict__ cls_cnt, float* __restrict__ bucket, int N)
{
    __shared__ int hist[CC];
    __shared__ int base[CC];
    __shared__ int loc[CC];
    const int tid = threadIdx.x;
    const int rowsPerBlock = N / gridDim.x;
    const int r0 = blockIdx.x * rowsPerBlock;
    const int r1 = r0 + rowsPerBlock;
    for (int c = tid; c < CC; c += blockDim.x) { hist[c] = 0; loc[c] = 0; }
    __syncthreads();
    for (int r = r0 + tid; r < r1; r += blockDim.x)
        atomicAdd(&hist[targets[r]], 1);
    __syncthreads();
    for (int c = tid; c < CC; c += blockDim.x)
        base[c] = (hist[c] > 0) ? atomicAdd(&cls_cnt[c], hist[c]) : 0;
    __syncthreads();
    for (int r = r0 + tid; r < r1; r += blockDim.x) {
        int c = targets[r];
        int idx = base[c] + atomicAdd(&loc[c], 1);
        if (idx < BUCKET) bucket[(size_t)c * BUCKET + idx] = pos[r];
    }
}

// --------- K2: per class, radix-select the m smallest positive scores ---------
__global__ __launch_bounds__(256) void k2_select(
    const float* __restrict__ bucket, const int* __restrict__ cls_cnt,
    float* __restrict__ u, int* __restrict__ m_arr, int* __restrict__ P_arr,
    float* __restrict__ wm_arr)
{
    __shared__ unsigned int keys[BUCKET];     // 16 KB
    __shared__ unsigned int hist[256];
    __shared__ unsigned int scan[256];
    __shared__ unsigned int sel[256];
    __shared__ unsigned int s_prefix;
    __shared__ int s_rank;
    __shared__ int cnt_lt;
    const int c   = blockIdx.x;
    const int tid = threadIdx.x;
    const int P = min(cls_cnt[c], BUCKET);
    double Kd = 0.95 * (double)P;
    int kf = (int)floor(Kd);
    int m = P - kf;
    if (m > MAXM) m = MAXM;
    if (m < 0) m = 0;
    if (tid == 0) {
        m_arr[c] = m; P_arr[c] = P;
        wm_arr[c] = (float)((double)(kf + 1) - Kd);   // fractional last-step weight
        s_prefix = 0; s_rank = m - 1; cnt_lt = 0;
    }
    for (int i = tid; i < P; i += 256) {
        unsigned int b = __float_as_uint(bucket[(size_t)c * BUCKET + i]);
        keys[i] = (b & 0x80000000u) ? ~b : (b | 0x80000000u);
    }
    __syncthreads();
    if (m == 0) return;

    for (int shift = 24; shift >= 0; shift -= 8) {
        hist[tid] = 0;
        __syncthreads();
        unsigned int pref = s_prefix;
        for (int i = tid; i < P; i += 256) {
            unsigned int k = keys[i];
            bool match = (shift == 24) || ((k >> (shift + 8)) == pref);
            if (match) atomicAdd(&hist[(k >> shift) & 255u], 1u);
        }
        __syncthreads();
        if (tid < 64) {   // single-wave inclusive scan of 256 bins (verified r1)
            unsigned h0 = hist[tid*4], h1 = hist[tid*4+1],
                     h2 = hist[tid*4+2], h3 = hist[tid*4+3];
            unsigned s0 = h0, s1 = s0 + h1, s2 = s1 + h2, s3 = s2 + h3;
            unsigned sc = s3;
            #pragma unroll
            for (int off = 1; off < 64; off <<= 1) {
                unsigned t2 = __shfl_up(sc, (unsigned)off, 64);
                if (tid >= off) sc += t2;
            }
            unsigned excl = sc - s3;
            scan[tid*4]   = excl + s0;
            scan[tid*4+1] = excl + s1;
            scan[tid*4+2] = excl + s2;
            scan[tid*4+3] = excl + s3;
        }
        __syncthreads();
        int r = s_rank;
        unsigned int inc = scan[tid];
        unsigned int exc = inc - hist[tid];
        __syncthreads();
        if ((unsigned int)r >= exc && (unsigned int)r < inc) {   // unique thread
            s_rank   = r - (int)exc;
            s_prefix = (pref << 8) | (unsigned int)tid;
        }
        __syncthreads();
    }
    const unsigned int kth = s_prefix;

    for (int i = tid; i < P; i += 256) {
        unsigned int k = keys[i];
        if (k < kth) {
            int pslot = atomicAdd(&cnt_lt, 1);
            sel[pslot] = k;
        }
    }
    __syncthreads();
    const int nlt = cnt_lt;
    for (int j = nlt + tid; j < 256; j += 256) sel[j] = (j < m) ? kth : 0xFFFFFFFFu;
    __syncthreads();
    for (int kk = 2; kk <= 256; kk <<= 1) {            // bitonic 256 ascending
        for (int j = kk >> 1; j > 0; j >>= 1) {
            int i = tid, ixj = tid ^ j;
            if (ixj > i) {
                unsigned int a = sel[i], b = sel[ixj];
                bool up = ((i & kk) == 0);
                if ((a > b) == up) { sel[i] = b; sel[ixj] = a; }
            }
            __syncthreads();
        }
    }
    if (tid < m) {
        unsigned int k = sel[tid];
        unsigned int b = (k & 0x80000000u) ? (k & 0x7fffffffu) : ~k;
        u[c * MAXM + tid] = __uint_as_float(b);        // m smallest, ascending
    }
}

// branchless uniform upper_bound over sorted prefix u[0..m-1]
__device__ __forceinline__ int ubound(const float* uc, int m, float key, int maxidx) {
    int l = 0;
    #pragma unroll
    for (int s = 128; s; s >>= 1) {
        int p = l + s - 1;
        float val = uc[p < maxidx ? p : maxidx];
        l += ((p < m) && (val <= key)) ? s : 0;
    }
    return l;
}

// --------- K3a: stream scores, per-lane LDS-atomic compaction.
//           LCAP=2048 -> 17KB LDS -> 8 blocks/CU (100% occupancy). ---------
__global__ __launch_bounds__(256) void k3a_stream(
    const float4* __restrict__ pred4, const float* __restrict__ L,
    const float* __restrict__ u, const int* __restrict__ m_arr,
    uint2* __restrict__ list, int* __restrict__ list_cnt, int list_cap,
    int* __restrict__ g_cnt, int* __restrict__ g_sum, int total4)
{
    __shared__ float umax_s[CC];
    __shared__ uint2 buf[LCAP];               // 16 KB
    __shared__ int lcnt;
    __shared__ int gbase;
    const int tid = threadIdx.x;
    if (tid < CC) {
        int m = m_arr[tid];
        umax_s[tid] = (m > 0) ? u[tid * MAXM + m - 1] : -INFINITY;
    }
    if (tid == 0) lcnt = 0;
    __syncthreads();

    auto proc = [&](float4 v, float Ln, int j) {
        float4 um = *((const float4*)&umax_s[j * 4]);
        float s0 = v.x - Ln, s1 = v.y - Ln, s2 = v.z - Ln, s3 = v.w - Ln;
        #pragma unroll
        for (int q = 0; q < 4; ++q) {
            float scv = (q == 0) ? s0 : (q == 1) ? s1 : (q == 2) ? s2 : s3;
            float mx  = (q == 0) ? um.x : (q == 1) ? um.y : (q == 2) ? um.z : um.w;
            if (scv < mx) {
                int c = j * 4 + q;
                int idx = atomicAdd(&lcnt, 1);
                if (idx < LCAP) {
                    buf[idx] = make_uint2((unsigned int)c, __float_as_uint(scv));
                } else {                       // LDS overflow: inline exact rank
                    int m = m_arr[c];
                    int l = ubound(u + c * MAXM, m, scv, MAXM - 1);
                    atomicAdd(&g_cnt[c], 1);
                    atomicAdd(&g_sum[c], m - 1 - l);
                }
            }
        }
    };

    const int stride = K3AGRID * 256;          // 262144
    int i = blockIdx.x * 256 + tid;
    while (i < total4) {                       // 2-deep load ILP (round-0 proven)
        int i2 = i + stride;
        bool has2 = (i2 < total4);
        float4 v0 = pred4[i];
        float4 v1 = has2 ? pred4[i2] : make_float4(0.f, 0.f, 0.f, 0.f);
        int n0 = i / 25, j0 = i - n0 * 25;
        float L0 = L[n0];
        proc(v0, L0, j0);
        if (has2) {
            int n1 = i2 / 25, j1 = i2 - n1 * 25;
            proc(v1, L[n1], j1);
        }
        i += 2 * stride;
    }
    __syncthreads();
    int cnt = min(lcnt, LCAP);
    if (tid == 0) gbase = atomicAdd(list_cnt, cnt);
    __syncthreads();
    const int base0 = gbase;
    for (int k = tid; k < cnt; k += 256) {
        int gi = base0 + k;
        if (gi < list_cap) {
            list[gi] = buf[k];
        } else {                               // global overflow: inline exact
            uint2 e = buf[k];
            int c = (int)e.x; float scv = __uint_as_float(e.y);
            int m = m_arr[c];
            int l = ubound(u + c * MAXM, m, scv, MAXM - 1);
            atomicAdd(&g_cnt[c], 1);
            atomicAdd(&g_sum[c], m - 1 - l);
        }
    }
}

// --------- K3b: dense rank vs LDS u-table.
//  R6: 8-way interleaved chains; ONE packed 64-bit LDS atomic per entry
//  (cnt<<32 | sum); finalize un-fused (no threadfence). ---------
__global__ __launch_bounds__(256) void k3b_rank(
    const uint2* __restrict__ list, const int* __restrict__ list_cnt, int list_cap,
    const float* __restrict__ u, const int* __restrict__ m_arr,
    int* __restrict__ g_cnt, int* __restrict__ g_sum)
{
    __shared__ float us[CC * USTRIDE];         // 64.4 KB
    __shared__ int sm[CC];
    __shared__ unsigned long long lpack[CC];   // cnt<<32 | sum (sum < 2^20 worst case)
    const int tid = threadIdx.x;
    for (int c = tid; c < CC; c += 256) { sm[c] = m_arr[c]; lpack[c] = 0ull; }
    for (int t = tid; t < CC * MAXM; t += 256) {
        int c = t / MAXM, k = t - c * MAXM;
        us[c * USTRIDE + k] = u[t];
    }
    __syncthreads();
    const int n = min(*list_cnt, list_cap);
    const int stride = K3BGRID * 256;
    for (int base = blockIdx.x * 256 + tid; base < n; base += 8 * stride) {
        int bb8[8]; int mm8[8]; float kk8[8]; bool hh8[8]; int cc8[8];
        #pragma unroll
        for (int t = 0; t < 8; ++t) {
            int idx = base + t * stride;
            bool h = idx < n;
            uint2 e = h ? list[idx] : make_uint2(0u, 0u);
            hh8[t] = h;
            cc8[t] = (int)e.x;
            bb8[t] = (int)e.x * USTRIDE;
            mm8[t] = h ? sm[(int)e.x] : 0;
            kk8[t] = __uint_as_float(e.y);
        }
        int ll8[8] = {0, 0, 0, 0, 0, 0, 0, 0};
        #pragma unroll
        for (int s = 128; s; s >>= 1) {        // 8 independent chains stepped together
            #pragma unroll
            for (int t = 0; t < 8; ++t) {
                int p = ll8[t] + s - 1;
                float val = us[bb8[t] + (p < USTRIDE - 1 ? p : USTRIDE - 1)];
                ll8[t] += ((p < mm8[t]) && (val <= kk8[t])) ? s : 0;
            }
        }
        #pragma unroll
        for (int t = 0; t < 8; ++t)
            if (hh8[t]) {
                unsigned long long pk =
                    (1ull << 32) | (unsigned long long)(unsigned)(mm8[t] - 1 - ll8[t]);
                atomicAdd(&lpack[cc8[t]], pk);
            }
    }
    __syncthreads();
    for (int c = tid; c < CC; c += 256) {
        unsigned long long pk = lpack[c];
        int cnt = (int)(pk >> 32);
        int sum = (int)(pk & 0xffffffffull);
        if (cnt) { atomicAdd(&g_cnt[c], cnt); atomicAdd(&g_sum[c], sum); }
    }
}

// ---------------- K4: finalize (round-0 proven) ----------------
__global__ __launch_bounds__(256) void k4_final(
    const float* __restrict__ ce_partial, int nPartial,
    const float* __restrict__ weight, const int* __restrict__ P_arr,
    const int* __restrict__ m_arr, const float* __restrict__ wm_arr,
    const int* __restrict__ g_cnt, const int* __restrict__ g_sum,
    float* __restrict__ out, int N)
{
    __shared__ double r1[256], r2[256], r3[256];
    double ce = 0.0;
    for (int i = threadIdx.x; i < nPartial; i += blockDim.x) ce += (double)ce_partial[i];
    double p = 0.0, wsum = 0.0;
    for (int c = threadIdx.x; c < CC; c += blockDim.x) {
        int P = P_arr[c], m = m_arr[c];
        double wgt = (double)weight[c];
        long long Nn = (long long)N - P;
        if (P > 0 && Nn > 0 && m > 0) {
            double wm = (double)wm_arr[c];
            double S   = (double)g_sum[c] + wm * (double)g_cnt[c];
            double sub = 0.5 * (double)(m - 1) * (double)(m - 2) + wm * (double)(m - 1);
            double pc  = (S - sub) / ((double)Nn * (double)P);
            if (pc < 0.0) pc = 0.0;
            p += pc * wgt;
        }
        wsum += wgt;
    }
    r1[threadIdx.x] = ce; r2[threadIdx.x] = p; r3[threadIdx.x] = wsum;
    __syncthreads();
    for (int off = blockDim.x >> 1; off; off >>= 1) {
        if ((int)threadIdx.x < off) {
            r1[threadIdx.x] += r1[threadIdx.x + off];
            r2[threadIdx.x] += r2[threadIdx.x + off];
            r3[threadIdx.x] += r3[threadIdx.x + off];
        }
        __syncthreads();
    }
    if (threadIdx.x == 0) {
        double ce_loss = r1[0] / (double)N;
        double avg = r2[0] / (r3[0] * 0.05);           // MAX_PAUC = R1-R0 = 0.05
        avg = fmin(fmax(avg, 0.0), 1.0);
        out[0] = (float)(0.5 * ce_loss + 0.5 * (1.0 - avg * avg));
    }
}

extern "C" void kernel_launch(void* const* d_in, const int* in_sizes, int n_in,
                              void* d_out, int out_size, void* d_ws, size_t ws_size,
                              hipStream_t stream) {
    (void)n_in; (void)out_size;
    const float* pred    = (const float*)d_in[0];
    const int*   targets = (const int*)d_in[1];
    const float* weight  = (const float*)d_in[2];
    float* out = (float*)d_out;
    const int N = in_sizes[1];

    const int K1_BLOCKS = N / TILE;                    // 4096
    char* base = (char*)d_ws;
    size_t off = 0;
    auto take = [&](size_t bytes) { char* q = base + off; off += (bytes + 15) & ~(size_t)15; return q; };
    float* L_ws       = (float*)take((size_t)N * 4);
    float* pos_ws     = (float*)take((size_t)N * 4);
    float* ce_partial = (float*)take((size_t)K1_BLOCKS * 4);
    float* u          = (float*)take((size_t)CC * MAXM * 4);
    int*   m_arr      = (int*)take(CC * 4);
    int*   P_arr      = (int*)take(CC * 4);
    float* wm_arr     = (float*)take(CC * 4);
    int*   zero_blk   = (int*)take(304 * 4);           // cls_cnt|g_cnt|g_sum|list_cnt
    int*   cls_cnt  = zero_blk;
    int*   g_cnt    = zero_blk + CC;
    int*   g_sum    = zero_blk + 2 * CC;
    int*   list_cnt = zero_blk + 3 * CC;
    float* bucket     = (float*)take((size_t)CC * BUCKET * 4);   // 1.6 MB
    uint2* list       = (uint2*)(base + off);
    long long rem     = (long long)ws_size - (long long)off;
    int list_cap      = (rem > 0) ? (int)(rem / 8) : 0;          // expected need ~1.3M entries

    hipMemsetAsync(zero_blk, 0, 304 * 4, stream);

    k1_tile<<<K1_BLOCKS, 256, 0, stream>>>(pred, targets, weight, L_ws, pos_ws,
                                           ce_partial, N);
    k1b_scatter<<<256, 256, 0, stream>>>(targets, pos_ws, cls_cnt, bucket, N);
    k2_select<<<CC, 256, 0, stream>>>(bucket, cls_cnt, u, m_arr, P_arr, wm_arr);
    const int total4 = (int)((size_t)N * CC / 4);
    k3a_stream<<<K3AGRID, 256, 0, stream>>>((const float4*)pred, L_ws, u, m_arr,
                                            list, list_cnt, list_cap, g_cnt, g_sum, total4);
    k3b_rank<<<K3BGRID, 256, 0, stream>>>(list, list_cnt, list_cap, u, m_arr,
                                          g_cnt, g_sum);
    k4_final<<<1, 256, 0, stream>>>(ce_partial, K1_BLOCKS, weight, P_arr, m_arr, wm_arr,
                                    g_cnt, g_sum, out, N);
}